// Round 1
// baseline (2994.786 us; speedup 1.0000x reference)
//
#include <hip/hip_runtime.h>
#include <math.h>

// ---------------------------------------------------------------------------
// Problem constants
// ---------------------------------------------------------------------------
namespace {
constexpr int BROWS = 8192;   // batch
constexpr int NLAB  = 4096;   // labeled rows (arange < NLAB)
constexpr int NUNL  = 4096;   // unlabeled rows
constexpr int CREAL = 100;    // classes
constexpr int CPAD  = 112;    // padded classes (zeros beyond 100; zeros are
                              // fixed points of the dynamics and contribute 0
                              // to entropy / norm / rowsum)
constexpr int DIM   = 512;    // embedding dim
constexpr int MAXIT = 30;

// workspace layout (float offsets). ~145.3 MB total.
constexpr size_t A_FLOATS = (size_t)BROWS * NUNL;          // A_t[k][i'] (k=0..8191, i'=i-4096)
constexpr size_t X_FLOATS = (size_t)BROWS * CPAD;
constexpr size_t P_FLOATS = (size_t)NUNL * CPAD;
constexpr size_t OFF_A    = 0;
constexpr size_t OFF_X0   = OFF_A + A_FLOATS;
constexpr size_t OFF_X1   = OFF_X0 + X_FLOATS;
constexpr size_t OFF_RN   = OFF_X1 + X_FLOATS;             // 1/row-norm, 8192
constexpr size_t OFF_PL   = OFF_RN + BROWS;                // P_lab  [4096][112] (static after iter 0)
constexpr size_t OFF_PU   = OFF_PL + P_FLOATS;             // P_unl  [4096][112] (per-iteration)
constexpr size_t OFF_H    = OFF_PU + P_FLOATS;             // entropy sum per unlabeled row
constexpr size_t OFF_ERR  = OFF_H + NUNL;                  // errsq[32] (one per iteration)
constexpr size_t OFF_MS   = OFF_ERR + 32;                  // double mean accumulator (8B aligned)
constexpr size_t OFF_FLAG = OFF_MS + 2;                    // converged flag (int)
constexpr size_t WS_FLOATS = OFF_FLAG + 2;
}

// ---------------------------------------------------------------------------
// 1/||embedds_row||  (clamped at 1e-12 like the reference)
// ---------------------------------------------------------------------------
__global__ __launch_bounds__(64) void k_rnorm(const float* __restrict__ emb,
                                              float* __restrict__ rn) {
  int row = blockIdx.x, l = threadIdx.x;
  const float4* e4 = (const float4*)(emb + (size_t)row * DIM);
  float4 a = e4[l], b = e4[l + 64];
  float s = a.x*a.x + a.y*a.y + a.z*a.z + a.w*a.w
          + b.x*b.x + b.y*b.y + b.z*b.z + b.w*b.w;
#pragma unroll
  for (int m = 1; m < 64; m <<= 1) s += __shfl_xor(s, m);
  if (l == 0) rn[row] = 1.0f / fmaxf(sqrtf(s), 1e-12f);
}

// ---------------------------------------------------------------------------
// X init: labeled rows one-hot, unlabeled uniform 1/C, pad cols zero.
// Written to BOTH ping-pong buffers (labeled rows are never rewritten).
// ---------------------------------------------------------------------------
__global__ __launch_bounds__(256) void k_initX(float* __restrict__ X0,
                                               float* __restrict__ X1,
                                               const int* __restrict__ labels) {
  int idx = blockIdx.x * 256 + threadIdx.x;        // < 8192*112
  int row = idx / CPAD, c = idx % CPAD;
  float v;
  if (row < NLAB) v = (c == labels[row]) ? 1.0f : 0.0f;
  else            v = (c < CREAL) ? 0.01f : 0.0f;
  X0[idx] = v;
  X1[idx] = v;
}

// ---------------------------------------------------------------------------
// MLP: 512 -> 256 -> 128 -> 64 -> 1  (ReLU between, none at end).
// 4 rows per block, weight loads coalesced + L2-resident.
// ---------------------------------------------------------------------------
__global__ __launch_bounds__(256) void k_mlp(const float* __restrict__ emb,
                                             const float* __restrict__ W1, const float* __restrict__ b1,
                                             const float* __restrict__ W2, const float* __restrict__ b2,
                                             const float* __restrict__ W3, const float* __restrict__ b3,
                                             const float* __restrict__ Wc, const float* __restrict__ bc,
                                             float* __restrict__ out) {
  __shared__ float xs[4][512];
  __shared__ float h1[4][256];
  __shared__ float h2[4][128];
  __shared__ float h3[4][64];
  int t = threadIdx.x;
  int r0 = blockIdx.x * 4;

  {
    const float4* src = (const float4*)(emb + (size_t)r0 * DIM);
    float4* dst = (float4*)&xs[0][0];
    dst[t] = src[t];
    dst[t + 256] = src[t + 256];
  }
  __syncthreads();

  { // layer 1: 256 cols, thread = col, 4 rows each
    float a0 = 0.f, a1 = 0.f, a2 = 0.f, a3 = 0.f;
    for (int k = 0; k < 512; k++) {
      float w = W1[k * 256 + t];
      a0 = fmaf(xs[0][k], w, a0);
      a1 = fmaf(xs[1][k], w, a1);
      a2 = fmaf(xs[2][k], w, a2);
      a3 = fmaf(xs[3][k], w, a3);
    }
    float bb = b1[t];
    h1[0][t] = fmaxf(a0 + bb, 0.f);
    h1[1][t] = fmaxf(a1 + bb, 0.f);
    h1[2][t] = fmaxf(a2 + bb, 0.f);
    h1[3][t] = fmaxf(a3 + bb, 0.f);
  }
  __syncthreads();

  { // layer 2: 128 cols; half-block handles 2 rows
    int c = t & 127, rb = (t >> 7) * 2;
    float a0 = 0.f, a1 = 0.f;
    for (int k = 0; k < 256; k++) {
      float w = W2[k * 128 + c];
      a0 = fmaf(h1[rb][k], w, a0);
      a1 = fmaf(h1[rb + 1][k], w, a1);
    }
    float bb = b2[c];
    h2[rb][c] = fmaxf(a0 + bb, 0.f);
    h2[rb + 1][c] = fmaxf(a1 + bb, 0.f);
  }
  __syncthreads();

  { // layer 3: 64 cols; quarter-block per row
    int c = t & 63, r = t >> 6;
    float a = 0.f;
    for (int k = 0; k < 128; k++) a = fmaf(h2[r][k], W3[k * 64 + c], a);
    h3[r][c] = fmaxf(a + b3[c], 0.f);
  }
  __syncthreads();

  { // head: wave w reduces row w
    int r = t >> 6, l = t & 63;
    float v = h3[r][l] * Wc[l];
#pragma unroll
    for (int m = 32; m; m >>= 1) v += __shfl_down(v, m);
    if (l == 0) out[r0 + r] = v + bc[0];
  }
}

// ---------------------------------------------------------------------------
// S = clamp(cos_sim, 0, 1), diag=0.  Computes the FULL 8192x8192 for the mean
// (double atomic) but stores only rows i>=4096, transposed: A_t[j][i-4096].
// 128x128 tile per block, 8x8 per thread, [row][k]-major LDS tiles (k padded).
// ---------------------------------------------------------------------------
__global__ __launch_bounds__(256) void k_sim(const float* __restrict__ emb,
                                             const float* __restrict__ rn,
                                             float* __restrict__ A_t,
                                             double* __restrict__ meansum) {
  __shared__ float Ea[128 * 20];
  __shared__ float Eb[128 * 20];
  __shared__ float redbuf[4];
  int t = threadIdx.x;
  int tx = t & 15, ty = t >> 4;          // tx along i, ty along j
  int i0 = blockIdx.x * 128, j0 = blockIdx.y * 128;
  float acc[8][8];
#pragma unroll
  for (int a = 0; a < 8; a++)
#pragma unroll
    for (int b = 0; b < 8; b++) acc[a][b] = 0.f;

  int lrow = t >> 2, lkq = (t & 3) * 4;
  for (int kt = 0; kt < DIM; kt += 16) {
    __syncthreads();
#pragma unroll
    for (int p = 0; p < 2; p++) {
      int r = lrow + p * 64;
      *(float4*)(Ea + r * 20 + lkq) = *(const float4*)(emb + (size_t)(i0 + r) * DIM + kt + lkq);
      *(float4*)(Eb + r * 20 + lkq) = *(const float4*)(emb + (size_t)(j0 + r) * DIM + kt + lkq);
    }
    __syncthreads();
#pragma unroll
    for (int kk = 0; kk < 16; kk += 4) {
      float4 a[8], b[8];
#pragma unroll
      for (int d = 0; d < 8; d++) a[d] = *(const float4*)(Ea + (tx + d * 16) * 20 + kk);
#pragma unroll
      for (int d = 0; d < 8; d++) b[d] = *(const float4*)(Eb + (ty + d * 16) * 20 + kk);
#pragma unroll
      for (int di = 0; di < 8; di++)
#pragma unroll
        for (int dj = 0; dj < 8; dj++) {
          acc[di][dj] = fmaf(a[di].x, b[dj].x, acc[di][dj]);
          acc[di][dj] = fmaf(a[di].y, b[dj].y, acc[di][dj]);
          acc[di][dj] = fmaf(a[di].z, b[dj].z, acc[di][dj]);
          acc[di][dj] = fmaf(a[di].w, b[dj].w, acc[di][dj]);
        }
    }
  }

  float rni[8], rnj[8];
#pragma unroll
  for (int d = 0; d < 8; d++) rni[d] = rn[i0 + tx + d * 16];
#pragma unroll
  for (int d = 0; d < 8; d++) rnj[d] = rn[j0 + ty + d * 16];

  float lsum = 0.f;
  bool dostore = (i0 >= NLAB);
#pragma unroll
  for (int di = 0; di < 8; di++) {
    int gi = i0 + tx + di * 16;
#pragma unroll
    for (int dj = 0; dj < 8; dj++) {
      int gj = j0 + ty + dj * 16;
      float s = acc[di][dj] * rni[di] * rnj[dj];
      if (gi == gj) s = 0.f;                       // fill_diagonal_(0) before clamp/mean
      s = fminf(fmaxf(s, 0.f), 1.f);
      lsum += s;
      if (dostore) A_t[(size_t)gj * NUNL + (gi - NLAB)] = s;
    }
  }
#pragma unroll
  for (int m = 1; m < 64; m <<= 1) lsum += __shfl_xor(lsum, m);
  if ((t & 63) == 0) redbuf[t >> 6] = lsum;
  __syncthreads();
  if (t == 0) atomicAdd(meansum, (double)(redbuf[0] + redbuf[1] + redbuf[2] + redbuf[3]));
}

// ---------------------------------------------------------------------------
// A = where(S < mean, 0, S); A = 1 - A   =>  s<mean ? 1.0 : 1.0-s  (in place)
// ---------------------------------------------------------------------------
__global__ __launch_bounds__(256) void k_thresh(float* __restrict__ A_t,
                                                const double* __restrict__ meansum) {
  float mean = (float)(*meansum * (1.0 / ((double)BROWS * (double)BROWS)));
  size_t idx = (size_t)blockIdx.x * 256 + threadIdx.x;   // over float4s
  float4* p = ((float4*)A_t) + idx;
  float4 v = *p;
  v.x = (v.x < mean) ? 1.0f : 1.0f - v.x;
  v.y = (v.y < mean) ? 1.0f : 1.0f - v.y;
  v.z = (v.z < mean) ? 1.0f : 1.0f - v.z;
  v.w = (v.w < mean) ? 1.0f : 1.0f - v.w;
  *p = v;
}

// ---------------------------------------------------------------------------
// Iteration GEMM: P += A_t[k-range]^T-slice @ X.  A streamed global->reg
// (coalesced float4, no reuse), X via broadcast global float4 loads.
// Block = 4 waves stacked on K (128 k each); wave tile = 64 rows x 112 cols;
// per-thread 4 rows x 28 cols (112 FMA/k). LDS cross-wave reduce, then one
// fp32 atomic pass into P (8 k-blocks => 8 atomic adds per element/iter).
// Gated on the device convergence flag (uniform -> no barrier divergence).
// ---------------------------------------------------------------------------
__global__ __launch_bounds__(256) void k_gemm(const float* __restrict__ A_t,
                                              const float* __restrict__ X,
                                              float* __restrict__ Plab,
                                              float* __restrict__ Punl,
                                              int kbase,
                                              const int* __restrict__ flag) {
  if (*flag) return;
  __shared__ float red[64 * 116];
  int t = threadIdx.x;
  int w = t >> 6, lane = t & 63;
  int rg = lane & 15, cg = lane >> 4;
  int i0 = blockIdx.x * 64;
  int kstart = kbase + blockIdx.y * 512 + w * 128;
  int r0 = i0 + rg * 4;
  int c0 = cg * 28;
  float* P = (kbase + (int)blockIdx.y * 512 < NLAB) ? Plab : Punl;

  float4 acc0[7], acc1[7], acc2[7], acc3[7];
#pragma unroll
  for (int m = 0; m < 7; m++) {
    acc0[m] = make_float4(0.f, 0.f, 0.f, 0.f);
    acc1[m] = make_float4(0.f, 0.f, 0.f, 0.f);
    acc2[m] = make_float4(0.f, 0.f, 0.f, 0.f);
    acc3[m] = make_float4(0.f, 0.f, 0.f, 0.f);
  }

  const float* pA = A_t + (size_t)kstart * NUNL + r0;
  const float* pX = X + (size_t)kstart * CPAD + c0;
#pragma unroll 2
  for (int k = 0; k < 128; k++) {
    float4 a = *(const float4*)pA;
    float4 xv[7];
#pragma unroll
    for (int m = 0; m < 7; m++) xv[m] = *(const float4*)(pX + m * 4);
    pA += NUNL;
    pX += CPAD;
#pragma unroll
    for (int m = 0; m < 7; m++) {
      float4 x = xv[m];
      acc0[m].x = fmaf(a.x, x.x, acc0[m].x); acc0[m].y = fmaf(a.x, x.y, acc0[m].y);
      acc0[m].z = fmaf(a.x, x.z, acc0[m].z); acc0[m].w = fmaf(a.x, x.w, acc0[m].w);
      acc1[m].x = fmaf(a.y, x.x, acc1[m].x); acc1[m].y = fmaf(a.y, x.y, acc1[m].y);
      acc1[m].z = fmaf(a.y, x.z, acc1[m].z); acc1[m].w = fmaf(a.y, x.w, acc1[m].w);
      acc2[m].x = fmaf(a.z, x.x, acc2[m].x); acc2[m].y = fmaf(a.z, x.y, acc2[m].y);
      acc2[m].z = fmaf(a.z, x.z, acc2[m].z); acc2[m].w = fmaf(a.z, x.w, acc2[m].w);
      acc3[m].x = fmaf(a.w, x.x, acc3[m].x); acc3[m].y = fmaf(a.w, x.y, acc3[m].y);
      acc3[m].z = fmaf(a.w, x.z, acc3[m].z); acc3[m].w = fmaf(a.w, x.w, acc3[m].w);
    }
  }

  // cross-wave reduce into LDS (wave 0 stores, waves 1..3 accumulate)
  for (int ww = 0; ww < 4; ww++) {
    if (w == ww) {
#pragma unroll
      for (int m = 0; m < 7; m++) {
        float4* s0 = (float4*)&red[(rg * 4 + 0) * 116 + c0 + m * 4];
        float4* s1 = (float4*)&red[(rg * 4 + 1) * 116 + c0 + m * 4];
        float4* s2 = (float4*)&red[(rg * 4 + 2) * 116 + c0 + m * 4];
        float4* s3 = (float4*)&red[(rg * 4 + 3) * 116 + c0 + m * 4];
        if (ww == 0) {
          *s0 = acc0[m]; *s1 = acc1[m]; *s2 = acc2[m]; *s3 = acc3[m];
        } else {
          float4 v;
          v = *s0; v.x += acc0[m].x; v.y += acc0[m].y; v.z += acc0[m].z; v.w += acc0[m].w; *s0 = v;
          v = *s1; v.x += acc1[m].x; v.y += acc1[m].y; v.z += acc1[m].z; v.w += acc1[m].w; *s1 = v;
          v = *s2; v.x += acc2[m].x; v.y += acc2[m].y; v.z += acc2[m].z; v.w += acc2[m].w; *s2 = v;
          v = *s3; v.x += acc3[m].x; v.y += acc3[m].y; v.z += acc3[m].z; v.w += acc3[m].w; *s3 = v;
        }
      }
    }
    __syncthreads();
  }

  // one atomic pass: thread t covers row t/4, cols (t&3) + 4m
  int row = t >> 2, q = t & 3;
  float* dst = P + (size_t)(i0 + row) * CPAD + q;
  const float* src = &red[row * 116 + q];
#pragma unroll
  for (int m = 0; m < 28; m++) atomicAdd(dst + m * 4, src[m * 4]);
}

// ---------------------------------------------------------------------------
// Epilogue: Xn = rownorm(Xold * (P_lab + P_unl)); entropy -> hist; ||dX||^2 ->
// errsq[iter]; write X ping-pong; zero P_unl for next iteration.
// One wave per unlabeled row (lanes <56 carry float2 = 112 cols).
// ---------------------------------------------------------------------------
__global__ __launch_bounds__(256) void k_epi(const float* __restrict__ Plab,
                                             float* __restrict__ Punl,
                                             const float* __restrict__ Xold,
                                             float* __restrict__ Xnew,
                                             float* __restrict__ hist,
                                             float* __restrict__ errsq,
                                             const int* __restrict__ flag,
                                             int iter) {
  if (*flag) return;
  int t = threadIdx.x;
  int w = t >> 6, lane = t & 63;
  int row = blockIdx.x * 4 + w;                       // unlabeled row index i' = i-4096
  bool act = lane < 56;
  size_t poff = (size_t)row * CPAD + lane * 2;
  size_t xoff = (size_t)(NLAB + row) * CPAD + lane * 2;
  float2 xo = make_float2(0.f, 0.f), xn = make_float2(0.f, 0.f);
  if (act) {
    float2 pl = *(const float2*)(Plab + poff);
    float2 pu = *(const float2*)(Punl + poff);
    xo = *(const float2*)(Xold + xoff);
    xn.x = xo.x * (pl.x + pu.x);
    xn.y = xo.y * (pl.y + pu.y);
  }
  float s = xn.x + xn.y;
#pragma unroll
  for (int m = 1; m < 64; m <<= 1) s += __shfl_xor(s, m);
  float inv = 1.0f / s;
  float ent = 0.f, dsq = 0.f;
  if (act) {
    xn.x *= inv; xn.y *= inv;
    ent = -(xn.x * log2f(xn.x + 1e-20f) + xn.y * log2f(xn.y + 1e-20f));
    float dx = xn.x - xo.x, dy = xn.y - xo.y;
    dsq = dx * dx + dy * dy;
    *(float2*)(Xnew + xoff) = xn;
    *(float2*)(Punl + poff) = make_float2(0.f, 0.f);  // ready for next iteration
  }
#pragma unroll
  for (int m = 1; m < 64; m <<= 1) { ent += __shfl_xor(ent, m); dsq += __shfl_xor(dsq, m); }
  if (lane == 0) {
    hist[row] += ent;                 // row is unique to this wave
    atomicAdd(&errsq[iter], dsq);
  }
}

// err = sqrt(errsq) <= TOL  <=>  errsq <= TOL^2
__global__ void k_flag(const float* __restrict__ errsq, int* __restrict__ flag, int iter) {
  if (*flag == 0 && errsq[iter] <= 1e-6f) *flag = 1;
}

// y_true = hist_sum/30 for unlabeled (0 for labeled); mask = i < 4096
__global__ __launch_bounds__(256) void k_final(const float* __restrict__ hist,
                                               float* __restrict__ out) {
  int i = blockIdx.x * 256 + threadIdx.x;   // 0..8191
  float yt = (i < NLAB) ? 0.0f : hist[i - NLAB] * (1.0f / 30.0f);
  out[BROWS + i] = yt;
  out[2 * BROWS + i] = (i < NLAB) ? 1.0f : 0.0f;
}

// ---------------------------------------------------------------------------
extern "C" void kernel_launch(void* const* d_in, const int* in_sizes, int n_in,
                              void* d_out, int out_size, void* d_ws, size_t ws_size,
                              hipStream_t stream) {
  const float* emb    = (const float*)d_in[1];
  const int*   labels = (const int*)d_in[2];
  const float* W1 = (const float*)d_in[3];
  const float* b1 = (const float*)d_in[4];
  const float* W2 = (const float*)d_in[5];
  const float* b2 = (const float*)d_in[6];
  const float* W3 = (const float*)d_in[7];
  const float* b3 = (const float*)d_in[8];
  const float* Wc = (const float*)d_in[9];
  const float* bc = (const float*)d_in[10];
  float* out = (float*)d_out;

  float* ws   = (float*)d_ws;
  float* A_t  = ws + OFF_A;
  float* X0   = ws + OFF_X0;
  float* X1   = ws + OFF_X1;
  float* rn   = ws + OFF_RN;
  float* Plab = ws + OFF_PL;
  float* Punl = ws + OFF_PU;
  float* hist = ws + OFF_H;
  float* errs = ws + OFF_ERR;
  double* ms  = (double*)(ws + OFF_MS);
  int*   flag = (int*)(ws + OFF_FLAG);

  // zero everything that's accumulated into (ws is poisoned 0xAA each call)
  hipMemsetAsync(ws + OFF_PL, 0, (WS_FLOATS - OFF_PL) * sizeof(float), stream);

  k_rnorm<<<BROWS, 64, 0, stream>>>(emb, rn);
  k_initX<<<(BROWS * CPAD) / 256, 256, 0, stream>>>(X0, X1, labels);
  k_mlp<<<BROWS / 4, 256, 0, stream>>>(emb, W1, b1, W2, b2, W3, b3, Wc, bc, out);

  { dim3 g(BROWS / 128, BROWS / 128); k_sim<<<g, 256, 0, stream>>>(emb, rn, A_t, ms); }
  k_thresh<<<(int)(A_FLOATS / 4 / 256), 256, 0, stream>>>(A_t, ms);

  for (int it = 0; it < MAXIT; it++) {
    const float* Xo = (it & 1) ? X1 : X0;
    float* Xn = (it & 1) ? X0 : X1;
    if (it == 0) {
      dim3 g(NUNL / 64, 16);                 // full K: labeled half -> P_lab (static)
      k_gemm<<<g, 256, 0, stream>>>(A_t, Xo, Plab, Punl, 0, flag);
    } else {
      dim3 g(NUNL / 64, 8);                  // only unlabeled half each iteration
      k_gemm<<<g, 256, 0, stream>>>(A_t, Xo, Plab, Punl, NLAB, flag);
    }
    k_epi<<<NUNL / 4, 256, 0, stream>>>(Plab, Punl, Xo, Xn, hist, errs, flag, it);
    k_flag<<<1, 1, 0, stream>>>(errs, flag, it);
  }

  k_final<<<BROWS / 256, 256, 0, stream>>>(hist, out);
}

// Round 2
// 1843.130 us; speedup vs baseline: 1.6248x; 1.6248x over previous
//
#include <hip/hip_runtime.h>
#include <hip/hip_bf16.h>
#include <math.h>

// ---------------------------------------------------------------------------
// Problem constants
// ---------------------------------------------------------------------------
namespace {
constexpr int BROWS = 8192;
constexpr int NLAB  = 4096;
constexpr int NUNL  = 4096;
constexpr int CREAL = 100;
constexpr int CPAD  = 112;    // 7 mfma col-tiles of 16
constexpr int DIM   = 512;
constexpr int MAXIT = 30;

constexpr size_t MB = 1ull << 20;
// byte offsets into ws (proven >=139.1 MB available from round 1 layout)
constexpr size_t OFF_AH   = 0;          // bf16 hi of A (pre-thresh: Sh)  [4096][8192] = 64 MB
constexpr size_t OFF_AL   = 64 * MB;    // bf16 lo                        = 64 MB
constexpr size_t OFF_XHT  = 128 * MB;   // bf16 X^T hi [112][8192] = 1.75 MB
constexpr size_t OFF_XLT  = 130 * MB;   // bf16 X^T lo
constexpr size_t OFF_XU   = 132 * MB;   // fp32 X unlabeled [4096][112] = 1.79 MB
constexpr size_t OFF_PLAB = 134 * MB;   // fp32 [4096][112]
constexpr size_t OFF_PUNL = 136 * MB;
constexpr size_t OFF_HIST = 138 * MB;               // fp32 [4096]
constexpr size_t OFF_ERR  = 138 * MB + 32768;       // fp32 [32]
constexpr size_t OFF_MS   = 138 * MB + 33024;       // double
constexpr size_t OFF_FLAG = 138 * MB + 33152;       // int
constexpr size_t OFF_RN   = 138 * MB + 65536;       // fp32 [8192] (32 KB)
constexpr size_t MEMSET_BEG = OFF_PLAB;
constexpr size_t MEMSET_LEN = OFF_RN - OFF_PLAB;    // P, hist, err, ms, flag
}

typedef __attribute__((ext_vector_type(8))) short short8;
typedef __attribute__((ext_vector_type(4))) float floatx4;

__device__ inline ushort f2bf(float f) {
  __hip_bfloat16 h = __float2bfloat16(f);
  union { __hip_bfloat16 b; ushort u; } c; c.b = h; return c.u;
}
__device__ inline float bf2f(ushort u) {
  union { ushort u; __hip_bfloat16 b; } c; c.u = u;
  return __bfloat162float(c.b);
}

// ---------------------------------------------------------------------------
// 1/||embedds_row|| (clamped at 1e-12)
// ---------------------------------------------------------------------------
__global__ __launch_bounds__(64) void k_rnorm(const float* __restrict__ emb,
                                              float* __restrict__ rn) {
  int row = blockIdx.x, l = threadIdx.x;
  const float4* e4 = (const float4*)(emb + (size_t)row * DIM);
  float4 a = e4[l], b = e4[l + 64];
  float s = a.x*a.x + a.y*a.y + a.z*a.z + a.w*a.w
          + b.x*b.x + b.y*b.y + b.z*b.z + b.w*b.w;
#pragma unroll
  for (int m = 1; m < 64; m <<= 1) s += __shfl_xor(s, m);
  if (l == 0) rn[row] = 1.0f / fmaxf(sqrtf(s), 1e-12f);
}

// ---------------------------------------------------------------------------
// X init: fp32 unlabeled block (row-major) for the epilogue
// ---------------------------------------------------------------------------
__global__ __launch_bounds__(256) void k_initXu(float* __restrict__ Xu) {
  int idx = blockIdx.x * 256 + threadIdx.x;     // < 4096*112
  int c = idx % CPAD;
  Xu[idx] = (c < CREAL) ? 0.01f : 0.0f;
}

// X^T init (bf16 h/l), [c][j] layout, coalesced along j
__global__ __launch_bounds__(256) void k_initXT(ushort* __restrict__ XhT,
                                                ushort* __restrict__ XlT,
                                                const int* __restrict__ labels) {
  int j = blockIdx.x * 256 + threadIdx.x;       // 0..8191
  int c = blockIdx.y;                            // 0..111
  float v;
  if (j < NLAB) v = (labels[j] == c) ? 1.0f : 0.0f;
  else          v = (c < CREAL) ? 0.01f : 0.0f;
  ushort h = f2bf(v);
  XhT[(size_t)c * BROWS + j] = h;
  XlT[(size_t)c * BROWS + j] = f2bf(v - bf2f(h));
}

// ---------------------------------------------------------------------------
// MLP 512->256->128->64->1 (unchanged from round 1; passed correctness)
// ---------------------------------------------------------------------------
__global__ __launch_bounds__(256) void k_mlp(const float* __restrict__ emb,
                                             const float* __restrict__ W1, const float* __restrict__ b1,
                                             const float* __restrict__ W2, const float* __restrict__ b2,
                                             const float* __restrict__ W3, const float* __restrict__ b3,
                                             const float* __restrict__ Wc, const float* __restrict__ bc,
                                             float* __restrict__ out) {
  __shared__ float xs[4][512];
  __shared__ float h1[4][256];
  __shared__ float h2[4][128];
  __shared__ float h3[4][64];
  int t = threadIdx.x;
  int r0 = blockIdx.x * 4;
  {
    const float4* src = (const float4*)(emb + (size_t)r0 * DIM);
    float4* dst = (float4*)&xs[0][0];
    dst[t] = src[t];
    dst[t + 256] = src[t + 256];
  }
  __syncthreads();
  {
    float a0 = 0.f, a1 = 0.f, a2 = 0.f, a3 = 0.f;
    for (int k = 0; k < 512; k++) {
      float w = W1[k * 256 + t];
      a0 = fmaf(xs[0][k], w, a0);
      a1 = fmaf(xs[1][k], w, a1);
      a2 = fmaf(xs[2][k], w, a2);
      a3 = fmaf(xs[3][k], w, a3);
    }
    float bb = b1[t];
    h1[0][t] = fmaxf(a0 + bb, 0.f);
    h1[1][t] = fmaxf(a1 + bb, 0.f);
    h1[2][t] = fmaxf(a2 + bb, 0.f);
    h1[3][t] = fmaxf(a3 + bb, 0.f);
  }
  __syncthreads();
  {
    int c = t & 127, rb = (t >> 7) * 2;
    float a0 = 0.f, a1 = 0.f;
    for (int k = 0; k < 256; k++) {
      float w = W2[k * 128 + c];
      a0 = fmaf(h1[rb][k], w, a0);
      a1 = fmaf(h1[rb + 1][k], w, a1);
    }
    float bb = b2[c];
    h2[rb][c] = fmaxf(a0 + bb, 0.f);
    h2[rb + 1][c] = fmaxf(a1 + bb, 0.f);
  }
  __syncthreads();
  {
    int c = t & 63, r = t >> 6;
    float a = 0.f;
    for (int k = 0; k < 128; k++) a = fmaf(h2[r][k], W3[k * 64 + c], a);
    h3[r][c] = fmaxf(a + b3[c], 0.f);
  }
  __syncthreads();
  {
    int r = t >> 6, l = t & 63;
    float v = h3[r][l] * Wc[l];
#pragma unroll
    for (int m = 32; m; m >>= 1) v += __shfl_down(v, m);
    if (l == 0) out[r0 + r] = v + bc[0];
  }
}

// ---------------------------------------------------------------------------
// Similarity via MFMA bf16x3.  S = clamp(E_i.E_j * rn_i * rn_j, 0, 1), diag 0.
// Full 8192x8192 computed for the mean (double atomic); rows i>=4096 stored
// as bf16 pair Sh/Sl in [i'][j] row-major.
// Block: 256 thr, tile 128x128; wave quadrant 64x64 = 4x4 mfma tiles.
// K staged in LDS 32 at a time, fp32 loaded from emb and h/l-split on the fly.
// ---------------------------------------------------------------------------
__global__ __launch_bounds__(256) void k_simM(const float* __restrict__ emb,
                                              const float* __restrict__ rn,
                                              ushort* __restrict__ Sh,
                                              ushort* __restrict__ Sl,
                                              double* __restrict__ meansum) {
  __shared__ ushort Eih[128 * 40];   // stride 40 elems = 80 B (16B-mult, 20-bank)
  __shared__ ushort Eil[128 * 40];
  __shared__ ushort Ejh[128 * 40];
  __shared__ ushort Ejl[128 * 40];
  __shared__ float redbuf[4];

  int t = threadIdx.x;
  int w = t >> 6, lane = t & 63;
  int m = lane & 15, g = lane >> 4;
  int ib = (w >> 1) * 64, jb = (w & 1) * 64;
  int i0 = blockIdx.x * 128, j0 = blockIdx.y * 128;

  floatx4 acc[4][4];
#pragma unroll
  for (int a = 0; a < 4; a++)
#pragma unroll
    for (int b = 0; b < 4; b++) acc[a][b] = (floatx4)0.0f;

  int lrow = t >> 1, lhalf = (t & 1) * 16;   // each thread stages 16 elems/buffer
  for (int kt = 0; kt < DIM; kt += 32) {
    __syncthreads();
    {
      const float4* gi = (const float4*)(emb + (size_t)(i0 + lrow) * DIM + kt + lhalf);
      const float4* gj = (const float4*)(emb + (size_t)(j0 + lrow) * DIM + kt + lhalf);
      float fi[16], fj[16];
#pragma unroll
      for (int q = 0; q < 4; q++) {
        float4 vi = gi[q], vj = gj[q];
        fi[q*4+0] = vi.x; fi[q*4+1] = vi.y; fi[q*4+2] = vi.z; fi[q*4+3] = vi.w;
        fj[q*4+0] = vj.x; fj[q*4+1] = vj.y; fj[q*4+2] = vj.z; fj[q*4+3] = vj.w;
      }
      union { short8 v; ushort u[8]; } ih0, ih1, il0, il1, jh0, jh1, jl0, jl1;
#pragma unroll
      for (int q = 0; q < 8; q++) {
        ushort h = f2bf(fi[q]);     ih0.u[q] = h; il0.u[q] = f2bf(fi[q] - bf2f(h));
        h = f2bf(fi[q + 8]);        ih1.u[q] = h; il1.u[q] = f2bf(fi[q+8] - bf2f(h));
        h = f2bf(fj[q]);            jh0.u[q] = h; jl0.u[q] = f2bf(fj[q] - bf2f(h));
        h = f2bf(fj[q + 8]);        jh1.u[q] = h; jl1.u[q] = f2bf(fj[q+8] - bf2f(h));
      }
      int o = lrow * 40 + lhalf;
      *(short8*)&Eih[o] = ih0.v; *(short8*)&Eih[o + 8] = ih1.v;
      *(short8*)&Eil[o] = il0.v; *(short8*)&Eil[o + 8] = il1.v;
      *(short8*)&Ejh[o] = jh0.v; *(short8*)&Ejh[o + 8] = jh1.v;
      *(short8*)&Ejl[o] = jl0.v; *(short8*)&Ejl[o + 8] = jl1.v;
    }
    __syncthreads();

    short8 ah[4], al[4], bh[4], bl[4];
#pragma unroll
    for (int rt = 0; rt < 4; rt++) {
      int o = (ib + rt * 16 + m) * 40 + g * 8;
      ah[rt] = *(const short8*)&Eih[o];
      al[rt] = *(const short8*)&Eil[o];
    }
#pragma unroll
    for (int ct = 0; ct < 4; ct++) {
      int o = (jb + ct * 16 + m) * 40 + g * 8;
      bh[ct] = *(const short8*)&Ejh[o];
      bl[ct] = *(const short8*)&Ejl[o];
    }
#pragma unroll
    for (int rt = 0; rt < 4; rt++)
#pragma unroll
      for (int ct = 0; ct < 4; ct++) {
        acc[rt][ct] = __builtin_amdgcn_mfma_f32_16x16x32_bf16(ah[rt], bh[ct], acc[rt][ct], 0, 0, 0);
        acc[rt][ct] = __builtin_amdgcn_mfma_f32_16x16x32_bf16(ah[rt], bl[ct], acc[rt][ct], 0, 0, 0);
        acc[rt][ct] = __builtin_amdgcn_mfma_f32_16x16x32_bf16(al[rt], bh[ct], acc[rt][ct], 0, 0, 0);
      }
  }

  // epilogue: scale, diag, clamp, mean-sum, store (C/D map: col=lane&15, row=g*4+r)
  bool dostore = (i0 >= NLAB);
  float lsum = 0.f;
#pragma unroll
  for (int rt = 0; rt < 4; rt++) {
    int gi0 = i0 + ib + rt * 16 + g * 4;
    float4 rni = *(const float4*)(rn + gi0);
#pragma unroll
    for (int ct = 0; ct < 4; ct++) {
      int gj = j0 + jb + ct * 16 + m;
      float rnj = rn[gj];
#pragma unroll
      for (int r = 0; r < 4; r++) {
        int gi = gi0 + r;
        float rv = (r == 0) ? rni.x : (r == 1) ? rni.y : (r == 2) ? rni.z : rni.w;
        float s = acc[rt][ct][r] * rv * rnj;
        if (gi == gj) s = 0.f;
        s = fminf(fmaxf(s, 0.f), 1.f);
        lsum += s;
        if (dostore) {
          size_t o = (size_t)(gi - NLAB) * BROWS + gj;
          ushort h = f2bf(s);
          Sh[o] = h;
          Sl[o] = f2bf(s - bf2f(h));
        }
      }
    }
  }
#pragma unroll
  for (int d = 1; d < 64; d <<= 1) lsum += __shfl_xor(lsum, d);
  if (lane == 0) redbuf[w] = lsum;
  __syncthreads();
  if (t == 0) atomicAdd(meansum, (double)(redbuf[0] + redbuf[1] + redbuf[2] + redbuf[3]));
}

// ---------------------------------------------------------------------------
// In-place: s = Sh+Sl; a = (s<mean)?1:1-s; re-split to bf16 pair (Ah,Al).
// ---------------------------------------------------------------------------
__global__ __launch_bounds__(256) void k_thresh(ushort* __restrict__ Sh,
                                                ushort* __restrict__ Sl,
                                                const double* __restrict__ meansum) {
  float mean = (float)(*meansum * (1.0 / ((double)BROWS * (double)BROWS)));
  size_t base = ((size_t)blockIdx.x * 256 + threadIdx.x) * 8;
#pragma unroll
  for (int q = 0; q < 2; q++) {
    ushort4 vh = *(ushort4*)(Sh + base + q * 4);
    ushort4 vl = *(ushort4*)(Sl + base + q * 4);
    ushort hs[4] = {vh.x, vh.y, vh.z, vh.w};
    ushort ls[4] = {vl.x, vl.y, vl.z, vl.w};
#pragma unroll
    for (int e = 0; e < 4; e++) {
      float s = bf2f(hs[e]) + bf2f(ls[e]);
      float a = (s < mean) ? 1.0f : 1.0f - s;
      ushort h = f2bf(a);
      hs[e] = h;
      ls[e] = f2bf(a - bf2f(h));
    }
    *(ushort4*)(Sh + base + q * 4) = make_ushort4(hs[0], hs[1], hs[2], hs[3]);
    *(ushort4*)(Sl + base + q * 4) = make_ushort4(ls[0], ls[1], ls[2], ls[3]);
  }
}

// ---------------------------------------------------------------------------
// Iteration GEMM via MFMA bf16x3: P[i'][c] += sum_j A[i'][j] * X[j][c].
// No LDS: A-frags stream global->VGPR ([i'][j] row-major, 16 rows x 64B lines
// per frag load), B-frags from X^T[c][j] with the identical lane pattern.
// Block 256 thr = 4 waves x 32 rows; tile 128 rows x 112 cols; k-chunk 256.
// fp32 atomics into Plab/Punl (16-way contention).
// ---------------------------------------------------------------------------
__global__ __launch_bounds__(256) void k_gemmM(const ushort* __restrict__ Ah,
                                               const ushort* __restrict__ Al,
                                               const ushort* __restrict__ XhT,
                                               const ushort* __restrict__ XlT,
                                               float* __restrict__ Plab,
                                               float* __restrict__ Punl,
                                               int kbase,
                                               const int* __restrict__ flag) {
  if (*flag) return;
  int t = threadIdx.x;
  int w = t >> 6, lane = t & 63;
  int m = lane & 15, g = lane >> 4;
  int i0 = blockIdx.x * 128;
  int kpos = kbase + blockIdx.y * 256;
  float* __restrict__ P = (kpos < NLAB) ? Plab : Punl;
  int row0 = i0 + w * 32;

  floatx4 acc[2][7];
#pragma unroll
  for (int a = 0; a < 2; a++)
#pragma unroll
    for (int b = 0; b < 7; b++) acc[a][b] = (floatx4)0.0f;

  for (int ks = 0; ks < 8; ks++) {
    int kk = kpos + ks * 32;
    short8 a_h[2], a_l[2], b_h[7], b_l[7];
#pragma unroll
    for (int rt = 0; rt < 2; rt++) {
      size_t ao = (size_t)(row0 + rt * 16 + m) * BROWS + kk + g * 8;
      a_h[rt] = *(const short8*)(Ah + ao);
      a_l[rt] = *(const short8*)(Al + ao);
    }
#pragma unroll
    for (int ct = 0; ct < 7; ct++) {
      size_t bo = (size_t)(ct * 16 + m) * BROWS + kk + g * 8;
      b_h[ct] = *(const short8*)(XhT + bo);
      b_l[ct] = *(const short8*)(XlT + bo);
    }
#pragma unroll
    for (int rt = 0; rt < 2; rt++)
#pragma unroll
      for (int ct = 0; ct < 7; ct++) {
        acc[rt][ct] = __builtin_amdgcn_mfma_f32_16x16x32_bf16(a_h[rt], b_h[ct], acc[rt][ct], 0, 0, 0);
        acc[rt][ct] = __builtin_amdgcn_mfma_f32_16x16x32_bf16(a_h[rt], b_l[ct], acc[rt][ct], 0, 0, 0);
        acc[rt][ct] = __builtin_amdgcn_mfma_f32_16x16x32_bf16(a_l[rt], b_h[ct], acc[rt][ct], 0, 0, 0);
      }
  }

#pragma unroll
  for (int rt = 0; rt < 2; rt++) {
    int rbase = row0 + rt * 16 + g * 4;
#pragma unroll
    for (int ct = 0; ct < 7; ct++) {
      int col = ct * 16 + m;
#pragma unroll
      for (int r = 0; r < 4; r++)
        atomicAdd(&P[(size_t)(rbase + r) * CPAD + col], acc[rt][ct][r]);
    }
  }
}

// ---------------------------------------------------------------------------
// Epilogue: Xn = rownorm(Xo * (Plab+Punl)); entropy->hist; ||dX||^2->errsq;
// in-place Xu update; write bf16 X^T h/l; zero Punl. One wave per row.
// ---------------------------------------------------------------------------
__global__ __launch_bounds__(256) void k_epi(const float* __restrict__ Plab,
                                             float* __restrict__ Punl,
                                             float* __restrict__ Xu,
                                             ushort* __restrict__ XhT,
                                             ushort* __restrict__ XlT,
                                             float* __restrict__ hist,
                                             float* __restrict__ errsq,
                                             const int* __restrict__ flag,
                                             int iter) {
  if (*flag) return;
  int t = threadIdx.x;
  int w = t >> 6, lane = t & 63;
  int row = blockIdx.x * 4 + w;                 // unlabeled row i' = i-4096
  bool act = lane < 56;
  size_t off = (size_t)row * CPAD + lane * 2;
  float2 xo = make_float2(0.f, 0.f), xn = make_float2(0.f, 0.f);
  if (act) {
    float2 pl = *(const float2*)(Plab + off);
    float2 pu = *(const float2*)(Punl + off);
    xo = *(const float2*)(Xu + off);
    xn.x = xo.x * (pl.x + pu.x);
    xn.y = xo.y * (pl.y + pu.y);
  }
  float s = xn.x + xn.y;
#pragma unroll
  for (int d = 1; d < 64; d <<= 1) s += __shfl_xor(s, d);
  float inv = 1.0f / s;
  float ent = 0.f, dsq = 0.f;
  if (act) {
    xn.x *= inv; xn.y *= inv;
    ent = -(xn.x * log2f(xn.x + 1e-20f) + xn.y * log2f(xn.y + 1e-20f));
    float dx = xn.x - xo.x, dy = xn.y - xo.y;
    dsq = dx * dx + dy * dy;
    *(float2*)(Xu + off) = xn;
    *(float2*)(Punl + off) = make_float2(0.f, 0.f);
    int c0 = lane * 2, jg = NLAB + row;
    ushort hx = f2bf(xn.x), hy = f2bf(xn.y);
    XhT[(size_t)c0 * BROWS + jg] = hx;
    XhT[(size_t)(c0 + 1) * BROWS + jg] = hy;
    XlT[(size_t)c0 * BROWS + jg] = f2bf(xn.x - bf2f(hx));
    XlT[(size_t)(c0 + 1) * BROWS + jg] = f2bf(xn.y - bf2f(hy));
  }
#pragma unroll
  for (int d = 1; d < 64; d <<= 1) { ent += __shfl_xor(ent, d); dsq += __shfl_xor(dsq, d); }
  if (lane == 0) {
    hist[row] += ent;
    atomicAdd(&errsq[iter], dsq);
  }
}

__global__ void k_flag(const float* __restrict__ errsq, int* __restrict__ flag, int iter) {
  if (*flag == 0 && errsq[iter] <= 1e-6f) *flag = 1;
}

__global__ __launch_bounds__(256) void k_final(const float* __restrict__ hist,
                                               float* __restrict__ out) {
  int i = blockIdx.x * 256 + threadIdx.x;
  float yt = (i < NLAB) ? 0.0f : hist[i - NLAB] * (1.0f / 30.0f);
  out[BROWS + i] = yt;
  out[2 * BROWS + i] = (i < NLAB) ? 1.0f : 0.0f;
}

// ---------------------------------------------------------------------------
extern "C" void kernel_launch(void* const* d_in, const int* in_sizes, int n_in,
                              void* d_out, int out_size, void* d_ws, size_t ws_size,
                              hipStream_t stream) {
  const float* emb    = (const float*)d_in[1];
  const int*   labels = (const int*)d_in[2];
  const float* W1 = (const float*)d_in[3];
  const float* b1 = (const float*)d_in[4];
  const float* W2 = (const float*)d_in[5];
  const float* b2 = (const float*)d_in[6];
  const float* W3 = (const float*)d_in[7];
  const float* b3 = (const float*)d_in[8];
  const float* Wc = (const float*)d_in[9];
  const float* bc = (const float*)d_in[10];
  float* out = (float*)d_out;

  char* ws = (char*)d_ws;
  ushort* Ahp  = (ushort*)(ws + OFF_AH);
  ushort* Alp  = (ushort*)(ws + OFF_AL);
  ushort* XhT  = (ushort*)(ws + OFF_XHT);
  ushort* XlT  = (ushort*)(ws + OFF_XLT);
  float*  Xu   = (float*)(ws + OFF_XU);
  float*  Plab = (float*)(ws + OFF_PLAB);
  float*  Punl = (float*)(ws + OFF_PUNL);
  float*  hist = (float*)(ws + OFF_HIST);
  float*  errs = (float*)(ws + OFF_ERR);
  double* ms   = (double*)(ws + OFF_MS);
  int*    flag = (int*)(ws + OFF_FLAG);
  float*  rn   = (float*)(ws + OFF_RN);

  hipMemsetAsync(ws + MEMSET_BEG, 0, MEMSET_LEN, stream);

  k_rnorm<<<BROWS, 64, 0, stream>>>(emb, rn);
  k_initXu<<<(NUNL * CPAD) / 256, 256, 0, stream>>>(Xu);
  { dim3 g(BROWS / 256, CPAD); k_initXT<<<g, 256, 0, stream>>>(XhT, XlT, labels); }
  k_mlp<<<BROWS / 4, 256, 0, stream>>>(emb, W1, b1, W2, b2, W3, b3, Wc, bc, out);

  { dim3 g(BROWS / 128, BROWS / 128); k_simM<<<g, 256, 0, stream>>>(emb, rn, Ahp, Alp, ms); }
  k_thresh<<<(int)((size_t)NUNL * BROWS / 8 / 256), 256, 0, stream>>>(Ahp, Alp, ms);

  for (int it = 0; it < MAXIT; it++) {
    if (it == 0) {
      dim3 g(NUNL / 128, 32);                 // full K (labeled half -> Plab)
      k_gemmM<<<g, 256, 0, stream>>>(Ahp, Alp, XhT, XlT, Plab, Punl, 0, flag);
    } else {
      dim3 g(NUNL / 128, 16);                 // unlabeled K only
      k_gemmM<<<g, 256, 0, stream>>>(Ahp, Alp, XhT, XlT, Plab, Punl, NLAB, flag);
    }
    k_epi<<<NUNL / 4, 256, 0, stream>>>(Plab, Punl, Xu, XhT, XlT, hist, errs, flag, it);
    k_flag<<<1, 1, 0, stream>>>(errs, flag, it);
  }

  k_final<<<BROWS / 256, 256, 0, stream>>>(hist, out);
}

// Round 3
// 1689.203 us; speedup vs baseline: 1.7729x; 1.0911x over previous
//
#include <hip/hip_runtime.h>
#include <hip/hip_bf16.h>
#include <math.h>

// ---------------------------------------------------------------------------
// Problem constants
// ---------------------------------------------------------------------------
namespace {
constexpr int BROWS = 8192;
constexpr int NLAB  = 4096;
constexpr int NUNL  = 4096;
constexpr int CREAL = 100;
constexpr int CPAD  = 112;    // 7 mfma col-tiles of 16
constexpr int DIM   = 512;
constexpr int MAXIT = 30;

constexpr size_t MiB = 1ull << 20;
// ws byte offsets. Proven budget >= ~138.5 MiB (round 1). Peak live: 136.1 MiB.
constexpr size_t OFF_SH  = 0;            // ushort [4096][8192] S hi -> A hi after it0 (64 MiB)
constexpr size_t OFF_SL  = 64 * MiB;     // S lo -> A lo (64 MiB)
constexpr size_t OFF_EL  = 128 * MiB;    // ushort [8192][512] emb bf16 low part (8 MiB, dead after k_simM)
// overlay of the EL region, used only after k_simM completes:
constexpr size_t OFF_XHT = 128 * MiB;    // ushort [112][8192] X^T hi (1.75 MiB)
constexpr size_t OFF_XLT = 130 * MiB;    // X^T lo
constexpr size_t OFF_XU  = 132 * MiB;    // fp32 [4096][112] unlabeled X
constexpr size_t OFF_PLB = 134 * MiB;    // fp32 [4096][112] P_lab (static after it0)
// tail (never overlaid):
constexpr size_t OFF_HIST = 136 * MiB;            // fp32 [4096]
constexpr size_t OFF_ERR  = 136 * MiB + 16384;    // fp32 [32]
constexpr size_t OFF_MS   = 136 * MiB + 16640;    // double mean accumulator
constexpr size_t TAIL_LEN = 16896;
}

typedef __attribute__((ext_vector_type(8))) short short8;
typedef __attribute__((ext_vector_type(4))) float floatx4;

__device__ inline ushort f2bf(float f) {
  __hip_bfloat16 h = __float2bfloat16(f);
  union { __hip_bfloat16 b; ushort u; } c; c.b = h; return c.u;
}
__device__ inline float bf2f(ushort u) {
  union { ushort u; __hip_bfloat16 b; } c; c.u = u;
  return __bfloat162float(c.b);
}

// ---------------------------------------------------------------------------
// 1/||embedds_row|| (clamped at 1e-12)
// ---------------------------------------------------------------------------
__global__ __launch_bounds__(64) void k_rnorm(const float* __restrict__ emb,
                                              float* __restrict__ rn) {
  int row = blockIdx.x, l = threadIdx.x;
  const float4* e4 = (const float4*)(emb + (size_t)row * DIM);
  float4 a = e4[l], b = e4[l + 64];
  float s = a.x*a.x + a.y*a.y + a.z*a.z + a.w*a.w
          + b.x*b.x + b.y*b.y + b.z*b.z + b.w*b.w;
#pragma unroll
  for (int m = 1; m < 64; m <<= 1) s += __shfl_xor(s, m);
  if (l == 0) rn[row] = 1.0f / fmaxf(sqrtf(s), 1e-12f);
}

// ---------------------------------------------------------------------------
// Precompute bf16 LOW part of emb: l = f - bf16(f).  (hi part is recomputed
// on the fly in k_simM: a single v_cvt per element.)
// ---------------------------------------------------------------------------
__global__ __launch_bounds__(256) void k_split(const float* __restrict__ emb,
                                               ushort* __restrict__ El) {
  size_t i8 = ((size_t)blockIdx.x * 256 + threadIdx.x) * 8;
  float4 v0 = *(const float4*)(emb + i8);
  float4 v1 = *(const float4*)(emb + i8 + 4);
  float f[8] = {v0.x, v0.y, v0.z, v0.w, v1.x, v1.y, v1.z, v1.w};
  union { short8 v; ushort u[8]; } l;
#pragma unroll
  for (int q = 0; q < 8; q++) {
    ushort h = f2bf(f[q]);
    l.u[q] = f2bf(f[q] - bf2f(h));
  }
  *(short8*)(El + i8) = l.v;
}

// ---------------------------------------------------------------------------
// X init (runs AFTER k_simM; overlays the El region)
// ---------------------------------------------------------------------------
__global__ __launch_bounds__(256) void k_initXu(float* __restrict__ Xu) {
  int idx = blockIdx.x * 256 + threadIdx.x;     // < 4096*112
  int c = idx % CPAD;
  Xu[idx] = (c < CREAL) ? 0.01f : 0.0f;
}

__global__ __launch_bounds__(256) void k_initXT(ushort* __restrict__ XhT,
                                                ushort* __restrict__ XlT,
                                                const int* __restrict__ labels) {
  int j = blockIdx.x * 256 + threadIdx.x;       // 0..8191
  int c = blockIdx.y;                            // 0..111
  float v;
  if (j < NLAB) v = (labels[j] == c) ? 1.0f : 0.0f;
  else          v = (c < CREAL) ? 0.01f : 0.0f;
  ushort h = f2bf(v);
  XhT[(size_t)c * BROWS + j] = h;
  XlT[(size_t)c * BROWS + j] = f2bf(v - bf2f(h));
}

// ---------------------------------------------------------------------------
// MLP 512->256->128->64->1 (unchanged; verified)
// ---------------------------------------------------------------------------
__global__ __launch_bounds__(256) void k_mlp(const float* __restrict__ emb,
                                             const float* __restrict__ W1, const float* __restrict__ b1,
                                             const float* __restrict__ W2, const float* __restrict__ b2,
                                             const float* __restrict__ W3, const float* __restrict__ b3,
                                             const float* __restrict__ Wc, const float* __restrict__ bc,
                                             float* __restrict__ out) {
  __shared__ float xs[4][512];
  __shared__ float h1[4][256];
  __shared__ float h2[4][128];
  __shared__ float h3[4][64];
  int t = threadIdx.x;
  int r0 = blockIdx.x * 4;
  {
    const float4* src = (const float4*)(emb + (size_t)r0 * DIM);
    float4* dst = (float4*)&xs[0][0];
    dst[t] = src[t];
    dst[t + 256] = src[t + 256];
  }
  __syncthreads();
  {
    float a0 = 0.f, a1 = 0.f, a2 = 0.f, a3 = 0.f;
    for (int k = 0; k < 512; k++) {
      float w = W1[k * 256 + t];
      a0 = fmaf(xs[0][k], w, a0);
      a1 = fmaf(xs[1][k], w, a1);
      a2 = fmaf(xs[2][k], w, a2);
      a3 = fmaf(xs[3][k], w, a3);
    }
    float bb = b1[t];
    h1[0][t] = fmaxf(a0 + bb, 0.f);
    h1[1][t] = fmaxf(a1 + bb, 0.f);
    h1[2][t] = fmaxf(a2 + bb, 0.f);
    h1[3][t] = fmaxf(a3 + bb, 0.f);
  }
  __syncthreads();
  {
    int c = t & 127, rb = (t >> 7) * 2;
    float a0 = 0.f, a1 = 0.f;
    for (int k = 0; k < 256; k++) {
      float w = W2[k * 128 + c];
      a0 = fmaf(h1[rb][k], w, a0);
      a1 = fmaf(h1[rb + 1][k], w, a1);
    }
    float bb = b2[c];
    h2[rb][c] = fmaxf(a0 + bb, 0.f);
    h2[rb + 1][c] = fmaxf(a1 + bb, 0.f);
  }
  __syncthreads();
  {
    int c = t & 63, r = t >> 6;
    float a = 0.f;
    for (int k = 0; k < 128; k++) a = fmaf(h2[r][k], W3[k * 64 + c], a);
    h3[r][c] = fmaxf(a + b3[c], 0.f);
  }
  __syncthreads();
  {
    int r = t >> 6, l = t & 63;
    float v = h3[r][l] * Wc[l];
#pragma unroll
    for (int m = 32; m; m >>= 1) v += __shfl_down(v, m);
    if (l == 0) out[r0 + r] = v + bc[0];
  }
}

// ---------------------------------------------------------------------------
// Similarity via MFMA bf16x3.  Stages: hi = cvt(emb fp32) on the fly (1 op),
// lo loaded pre-split from El.  Stores S rows i>=4096 as bf16 pair, [i'][j].
// ---------------------------------------------------------------------------
__global__ __launch_bounds__(256) void k_simM(const float* __restrict__ emb,
                                              const ushort* __restrict__ El,
                                              const float* __restrict__ rn,
                                              ushort* __restrict__ Sh,
                                              ushort* __restrict__ Sl,
                                              double* __restrict__ meansum) {
  __shared__ ushort Eih[128 * 40];
  __shared__ ushort Eil[128 * 40];
  __shared__ ushort Ejh[128 * 40];
  __shared__ ushort Ejl[128 * 40];
  __shared__ float redbuf[4];

  int t = threadIdx.x;
  int w = t >> 6, lane = t & 63;
  int m = lane & 15, g = lane >> 4;
  int ib = (w >> 1) * 64, jb = (w & 1) * 64;
  int i0 = blockIdx.x * 128, j0 = blockIdx.y * 128;

  floatx4 acc[4][4];
#pragma unroll
  for (int a = 0; a < 4; a++)
#pragma unroll
    for (int b = 0; b < 4; b++) acc[a][b] = (floatx4)0.0f;

  int lrow = t >> 1, lhalf = (t & 1) * 16;
  for (int kt = 0; kt < DIM; kt += 32) {
    __syncthreads();
    {
      const float*  gfi = emb + (size_t)(i0 + lrow) * DIM + kt + lhalf;
      const float*  gfj = emb + (size_t)(j0 + lrow) * DIM + kt + lhalf;
      const ushort* gli = El  + (size_t)(i0 + lrow) * DIM + kt + lhalf;
      const ushort* glj = El  + (size_t)(j0 + lrow) * DIM + kt + lhalf;
      float fi[16], fj[16];
#pragma unroll
      for (int q = 0; q < 4; q++) {
        float4 vi = ((const float4*)gfi)[q], vj = ((const float4*)gfj)[q];
        fi[q*4+0] = vi.x; fi[q*4+1] = vi.y; fi[q*4+2] = vi.z; fi[q*4+3] = vi.w;
        fj[q*4+0] = vj.x; fj[q*4+1] = vj.y; fj[q*4+2] = vj.z; fj[q*4+3] = vj.w;
      }
      union { short8 v; ushort u[8]; } ih0, ih1, jh0, jh1;
#pragma unroll
      for (int q = 0; q < 8; q++) {
        ih0.u[q] = f2bf(fi[q]);  ih1.u[q] = f2bf(fi[q + 8]);
        jh0.u[q] = f2bf(fj[q]);  jh1.u[q] = f2bf(fj[q + 8]);
      }
      int o = lrow * 40 + lhalf;
      *(short8*)&Eih[o] = ih0.v; *(short8*)&Eih[o + 8] = ih1.v;
      *(short8*)&Ejh[o] = jh0.v; *(short8*)&Ejh[o + 8] = jh1.v;
      *(short8*)&Eil[o] = *(const short8*)gli; *(short8*)&Eil[o + 8] = *(const short8*)(gli + 8);
      *(short8*)&Ejl[o] = *(const short8*)glj; *(short8*)&Ejl[o + 8] = *(const short8*)(glj + 8);
    }
    __syncthreads();

    short8 ah[4], al[4], bh[4], bl[4];
#pragma unroll
    for (int rt = 0; rt < 4; rt++) {
      int o = (ib + rt * 16 + m) * 40 + g * 8;
      ah[rt] = *(const short8*)&Eih[o];
      al[rt] = *(const short8*)&Eil[o];
    }
#pragma unroll
    for (int ct = 0; ct < 4; ct++) {
      int o = (jb + ct * 16 + m) * 40 + g * 8;
      bh[ct] = *(const short8*)&Ejh[o];
      bl[ct] = *(const short8*)&Ejl[o];
    }
#pragma unroll
    for (int rt = 0; rt < 4; rt++)
#pragma unroll
      for (int ct = 0; ct < 4; ct++) {
        acc[rt][ct] = __builtin_amdgcn_mfma_f32_16x16x32_bf16(ah[rt], bh[ct], acc[rt][ct], 0, 0, 0);
        acc[rt][ct] = __builtin_amdgcn_mfma_f32_16x16x32_bf16(ah[rt], bl[ct], acc[rt][ct], 0, 0, 0);
        acc[rt][ct] = __builtin_amdgcn_mfma_f32_16x16x32_bf16(al[rt], bh[ct], acc[rt][ct], 0, 0, 0);
      }
  }

  // epilogue (C/D map: col=lane&15, row=(lane>>4)*4+reg — verified r2)
  bool dostore = (i0 >= NLAB);
  float lsum = 0.f;
#pragma unroll
  for (int rt = 0; rt < 4; rt++) {
    int gi0 = i0 + ib + rt * 16 + g * 4;
    float4 rni = *(const float4*)(rn + gi0);
#pragma unroll
    for (int ct = 0; ct < 4; ct++) {
      int gj = j0 + jb + ct * 16 + m;
      float rnj = rn[gj];
#pragma unroll
      for (int r = 0; r < 4; r++) {
        int gi = gi0 + r;
        float rv = (r == 0) ? rni.x : (r == 1) ? rni.y : (r == 2) ? rni.z : rni.w;
        float s = acc[rt][ct][r] * rv * rnj;
        if (gi == gj) s = 0.f;
        s = fminf(fmaxf(s, 0.f), 1.f);
        lsum += s;
        if (dostore) {
          size_t o = (size_t)(gi - NLAB) * BROWS + gj;
          ushort h = f2bf(s);
          __builtin_nontemporal_store(h, Sh + o);
          __builtin_nontemporal_store(f2bf(s - bf2f(h)), Sl + o);
        }
      }
    }
  }
#pragma unroll
  for (int d = 1; d < 64; d <<= 1) lsum += __shfl_xor(lsum, d);
  if (lane == 0) redbuf[w] = lsum;
  __syncthreads();
  if (t == 0) atomicAdd(meansum, (double)(redbuf[0] + redbuf[1] + redbuf[2] + redbuf[3]));
}

// ---------------------------------------------------------------------------
// Fused iteration kernel.  256 blocks x 512 thr (8 waves).  Block owns 16
// unlabeled rows for the FULL K -> no cross-block atomics.  Waves split K;
// LDS-reduce 8 partials; fused epilogue (rownorm/entropy/errsq/X^T write).
// it==0: reads raw S, applies mean-threshold in registers, writes A back
// in-place (only own rows -> race-free), stores Plab (static).
// Convergence: skip iff errsq[it-1] <= TOL^2 (skipped iters leave errsq=0,
// so the skip chains -> matches the reference while-loop exactly).
// ---------------------------------------------------------------------------
__global__ __launch_bounds__(512) void k_iter(ushort* __restrict__ Ah,
                                              ushort* __restrict__ Al,
                                              const ushort* __restrict__ XhT,
                                              const ushort* __restrict__ XlT,
                                              ushort* __restrict__ XhTw,
                                              ushort* __restrict__ XlTw,
                                              float* __restrict__ Xu,
                                              float* __restrict__ Plab,
                                              float* __restrict__ hist,
                                              float* __restrict__ errsq,
                                              const double* __restrict__ ms,
                                              int it) {
  if (it > 0 && errsq[it - 1] <= 1e-6f) return;
  __shared__ float part[8][16 * 113];   // 57856 B
  __shared__ float Pbuf[16 * 114];      //  7296 B  (even stride for float2)
  int t = threadIdx.x;
  int w = t >> 6, lane = t & 63;
  int m = lane & 15, g = lane >> 4;
  int r0 = blockIdx.x * 16;             // unlabeled row base (i' space)

  int kw, nch;
  if (it == 0) { kw = w * 1024; nch = 32; }
  else         { kw = NLAB + w * 512; nch = 16; }
  float mean = 0.f;
  if (it == 0) mean = (float)(ms[0] * (1.0 / ((double)BROWS * (double)BROWS)));

  floatx4 acc[7];
#pragma unroll
  for (int c = 0; c < 7; c++) acc[c] = (floatx4)0.0f;

  for (int ks = 0; ks < nch; ks++) {
    int kk = kw + ks * 32;
    size_t ao = (size_t)(r0 + m) * BROWS + kk + g * 8;
    short8 a_h = __builtin_nontemporal_load((const short8*)(Ah + ao));
    short8 a_l = __builtin_nontemporal_load((const short8*)(Al + ao));
    if (it == 0) {
      union { short8 v; ushort u[8]; } uh, ul;
      uh.v = a_h; ul.v = a_l;
#pragma unroll
      for (int e = 0; e < 8; e++) {
        float s = bf2f(uh.u[e]) + bf2f(ul.u[e]);
        float a = (s < mean) ? 1.0f : 1.0f - s;
        ushort hh = f2bf(a);
        uh.u[e] = hh;
        ul.u[e] = f2bf(a - bf2f(hh));
      }
      a_h = uh.v; a_l = ul.v;
      __builtin_nontemporal_store(a_h, (short8*)(Ah + ao));
      __builtin_nontemporal_store(a_l, (short8*)(Al + ao));
    }
#pragma unroll
    for (int ct = 0; ct < 7; ct++) {
      size_t bo = (size_t)(ct * 16 + m) * BROWS + kk + g * 8;
      short8 b_h = *(const short8*)(XhT + bo);
      short8 b_l = *(const short8*)(XlT + bo);
      acc[ct] = __builtin_amdgcn_mfma_f32_16x16x32_bf16(a_h, b_h, acc[ct], 0, 0, 0);
      acc[ct] = __builtin_amdgcn_mfma_f32_16x16x32_bf16(a_h, b_l, acc[ct], 0, 0, 0);
      acc[ct] = __builtin_amdgcn_mfma_f32_16x16x32_bf16(a_l, b_h, acc[ct], 0, 0, 0);
    }
  }

  // wave partials -> LDS  (D row = g*4+r, col = ct*16+m)
#pragma unroll
  for (int ct = 0; ct < 7; ct++)
#pragma unroll
    for (int r = 0; r < 4; r++)
      part[w][(g * 4 + r) * 113 + ct * 16 + m] = acc[ct][r];
  __syncthreads();

  // reduce 8 partials; add Plab (it>0) or store it (it==0); P -> Pbuf
  for (int idx = t; idx < 16 * CPAD; idx += 512) {
    int row = idx / CPAD, col = idx % CPAD;
    int o = row * 113 + col;
    float s03 = part[0][o] + part[1][o] + part[2][o] + part[3][o];
    float s47 = part[4][o] + part[5][o] + part[6][o] + part[7][o];
    float P;
    size_t go = (size_t)(r0 + row) * CPAD + col;
    if (it == 0) {
      Plab[go] = s03;          // k<4096 half is the static labeled part
      P = s03 + s47;
    } else {
      P = s03 + s47 + Plab[go];
    }
    Pbuf[row * 114 + col] = P;
  }
  __syncthreads();

  // fused epilogue: wave w handles rows 2w, 2w+1 (56 lanes x float2 = 112)
  float dsq_acc = 0.f;
#pragma unroll
  for (int rr = 0; rr < 2; rr++) {
    int row = w * 2 + rr;
    int gr = r0 + row;
    bool act = lane < 56;
    float2 p = make_float2(0.f, 0.f), xo = make_float2(0.f, 0.f);
    if (act) {
      p = *(const float2*)&Pbuf[row * 114 + lane * 2];
      xo = *(const float2*)(Xu + (size_t)gr * CPAD + lane * 2);
    }
    float2 xn;
    xn.x = xo.x * p.x;
    xn.y = xo.y * p.y;
    float s = xn.x + xn.y;
#pragma unroll
    for (int d = 1; d < 64; d <<= 1) s += __shfl_xor(s, d);
    float inv = 1.0f / s;
    float ent = 0.f, dsq = 0.f;
    if (act) {
      xn.x *= inv; xn.y *= inv;
      ent = -(xn.x * log2f(xn.x + 1e-20f) + xn.y * log2f(xn.y + 1e-20f));
      float dx = xn.x - xo.x, dy = xn.y - xo.y;
      dsq = dx * dx + dy * dy;
      *(float2*)(Xu + (size_t)gr * CPAD + lane * 2) = xn;
      int c0 = lane * 2, jg = NLAB + gr;
      ushort hx = f2bf(xn.x), hy = f2bf(xn.y);
      XhTw[(size_t)c0 * BROWS + jg] = hx;
      XhTw[(size_t)(c0 + 1) * BROWS + jg] = hy;
      XlTw[(size_t)c0 * BROWS + jg] = f2bf(xn.x - bf2f(hx));
      XlTw[(size_t)(c0 + 1) * BROWS + jg] = f2bf(xn.y - bf2f(hy));
    }
#pragma unroll
    for (int d = 1; d < 64; d <<= 1) { ent += __shfl_xor(ent, d); dsq += __shfl_xor(dsq, d); }
    if (lane == 0) {
      hist[gr] += ent;
      dsq_acc += dsq;
    }
  }
  if (lane == 0) atomicAdd(&errsq[it], dsq_acc);
}

__global__ __launch_bounds__(256) void k_final(const float* __restrict__ hist,
                                               float* __restrict__ out) {
  int i = blockIdx.x * 256 + threadIdx.x;
  float yt = (i < NLAB) ? 0.0f : hist[i - NLAB] * (1.0f / 30.0f);
  out[BROWS + i] = yt;
  out[2 * BROWS + i] = (i < NLAB) ? 1.0f : 0.0f;
}

// ---------------------------------------------------------------------------
extern "C" void kernel_launch(void* const* d_in, const int* in_sizes, int n_in,
                              void* d_out, int out_size, void* d_ws, size_t ws_size,
                              hipStream_t stream) {
  const float* emb    = (const float*)d_in[1];
  const int*   labels = (const int*)d_in[2];
  const float* W1 = (const float*)d_in[3];
  const float* b1 = (const float*)d_in[4];
  const float* W2 = (const float*)d_in[5];
  const float* b2 = (const float*)d_in[6];
  const float* W3 = (const float*)d_in[7];
  const float* b3 = (const float*)d_in[8];
  const float* Wc = (const float*)d_in[9];
  const float* bc = (const float*)d_in[10];
  float* out = (float*)d_out;

  char* ws = (char*)d_ws;
  ushort* Sh   = (ushort*)(ws + OFF_SH);
  ushort* Sl   = (ushort*)(ws + OFF_SL);
  ushort* El   = (ushort*)(ws + OFF_EL);
  ushort* XhT  = (ushort*)(ws + OFF_XHT);
  ushort* XlT  = (ushort*)(ws + OFF_XLT);
  float*  Xu   = (float*)(ws + OFF_XU);
  float*  Plab = (float*)(ws + OFF_PLB);
  float*  hist = (float*)(ws + OFF_HIST);
  float*  errs = (float*)(ws + OFF_ERR);
  double* ms   = (double*)(ws + OFF_MS);
  // rn: borrow the tail of the Plab slot region? No — use space after MS.
  float*  rn   = (float*)(ws + OFF_MS + 256);     // fp32[8192] = 32 KB, inside tail pad

  // zero hist/errsq/ms (+ rn area harmlessly)
  hipMemsetAsync(ws + OFF_HIST, 0, TAIL_LEN + 256 + 32768, stream);

  k_rnorm<<<BROWS, 64, 0, stream>>>(emb, rn);
  k_split<<<(BROWS * DIM) / 8 / 256, 256, 0, stream>>>(emb, El);
  k_mlp<<<BROWS / 4, 256, 0, stream>>>(emb, W1, b1, W2, b2, W3, b3, Wc, bc, out);

  { dim3 g(BROWS / 128, BROWS / 128); k_simM<<<g, 256, 0, stream>>>(emb, El, rn, Sh, Sl, ms); }

  // overlay init (El is dead now)
  k_initXu<<<(NUNL * CPAD) / 256, 256, 0, stream>>>(Xu);
  { dim3 g(BROWS / 256, CPAD); k_initXT<<<g, 256, 0, stream>>>(XhT, XlT, labels); }

  for (int it = 0; it < MAXIT; it++) {
    k_iter<<<NUNL / 16, 512, 0, stream>>>(Sh, Sl, XhT, XlT, XhT, XlT, Xu, Plab,
                                          hist, errs, ms, it);
  }

  k_final<<<BROWS / 256, 256, 0, stream>>>(hist, out);
}

// Round 4
// 992.154 us; speedup vs baseline: 3.0185x; 1.7026x over previous
//
#include <hip/hip_runtime.h>
#include <hip/hip_bf16.h>
#include <math.h>

// ---------------------------------------------------------------------------
// Problem constants
// ---------------------------------------------------------------------------
namespace {
constexpr int BROWS = 8192;
constexpr int NLAB  = 4096;
constexpr int NUNL  = 4096;
constexpr int CREAL = 100;
constexpr int CPAD  = 112;    // 7 mfma col-tiles of 16
constexpr int DIM   = 512;
constexpr int MAXIT = 30;

constexpr size_t MiB = 1ull << 20;
// ws byte offsets (total use < 73 MiB; budget proven ~138 MiB)
constexpr size_t OFF_A    = 0;              // ushort[4096][8192] S -> A   64 MiB
constexpr size_t OFF_EB   = 64 * MiB;       // ushort[8192][512] emb bf16   8 MiB (dead after simM)
constexpr size_t OFF_XT0  = 64 * MiB;       // overlay: ushort[112][8192] X^T ping
constexpr size_t OFF_XT1  = 66 * MiB;       // X^T pong
constexpr size_t OFF_XU   = 68 * MiB;       // float[4096][112] exact X (unlabeled)
constexpr size_t OFF_PL   = 70 * MiB;       // float[4096][112] P_lab (static after it0)
constexpr size_t OFF_HIST = 72 * MiB;       // float[4096]
constexpr size_t OFF_ERR  = 72 * MiB + 16384;   // float[32]
constexpr size_t OFF_MS   = 72 * MiB + 16512;   // double (8B aligned)
constexpr size_t OFF_RN   = 72 * MiB + 32768;   // float[8192]
}

typedef __attribute__((ext_vector_type(8))) short short8;
typedef __attribute__((ext_vector_type(4))) float floatx4;

__device__ inline ushort f2bf(float f) {
  __hip_bfloat16 h = __float2bfloat16(f);
  union { __hip_bfloat16 b; ushort u; } c; c.b = h; return c.u;
}
__device__ inline float bf2f(ushort u) {
  union { ushort u; __hip_bfloat16 b; } c; c.u = u;
  return __bfloat162float(c.b);
}

// ---------------------------------------------------------------------------
// 1/||embedds_row|| (clamped at 1e-12)
// ---------------------------------------------------------------------------
__global__ __launch_bounds__(64) void k_rnorm(const float* __restrict__ emb,
                                              float* __restrict__ rn) {
  int row = blockIdx.x, l = threadIdx.x;
  const float4* e4 = (const float4*)(emb + (size_t)row * DIM);
  float4 a = e4[l], b = e4[l + 64];
  float s = a.x*a.x + a.y*a.y + a.z*a.z + a.w*a.w
          + b.x*b.x + b.y*b.y + b.z*b.z + b.w*b.w;
#pragma unroll
  for (int m = 1; m < 64; m <<= 1) s += __shfl_xor(s, m);
  if (l == 0) rn[row] = 1.0f / fmaxf(sqrtf(s), 1e-12f);
}

// ---------------------------------------------------------------------------
// emb fp32 -> bf16 (single), once.  simM staging becomes a pure copy.
// ---------------------------------------------------------------------------
__global__ __launch_bounds__(256) void k_prep(const float* __restrict__ emb,
                                              ushort* __restrict__ Eb) {
  size_t i8 = ((size_t)blockIdx.x * 256 + threadIdx.x) * 8;
  float4 v0 = *(const float4*)(emb + i8);
  float4 v1 = *(const float4*)(emb + i8 + 4);
  float f[8] = {v0.x, v0.y, v0.z, v0.w, v1.x, v1.y, v1.z, v1.w};
  union { short8 v; ushort u[8]; } o;
#pragma unroll
  for (int q = 0; q < 8; q++) o.u[q] = f2bf(f[q]);
  *(short8*)(Eb + i8) = o.v;
}

// ---------------------------------------------------------------------------
// X init: exact fp32 X (unlabeled rows) + bf16 X^T in BOTH ping-pong buffers
// ---------------------------------------------------------------------------
__global__ __launch_bounds__(256) void k_initXu(float* __restrict__ Xu) {
  int idx = blockIdx.x * 256 + threadIdx.x;     // < 4096*112
  int c = idx % CPAD;
  Xu[idx] = (c < CREAL) ? 0.01f : 0.0f;
}

__global__ __launch_bounds__(256) void k_initXT(ushort* __restrict__ X0,
                                                ushort* __restrict__ X1,
                                                const int* __restrict__ labels) {
  int j = blockIdx.x * 256 + threadIdx.x;       // 0..8191
  int c = blockIdx.y;                            // 0..111
  float v;
  if (j < NLAB) v = (labels[j] == c) ? 1.0f : 0.0f;
  else          v = (c < CREAL) ? 0.01f : 0.0f;
  ushort b = f2bf(v);
  X0[(size_t)c * BROWS + j] = b;
  X1[(size_t)c * BROWS + j] = b;
}

// ---------------------------------------------------------------------------
// MLP 512->256->128->64->1 (unchanged; verified)
// ---------------------------------------------------------------------------
__global__ __launch_bounds__(256) void k_mlp(const float* __restrict__ emb,
                                             const float* __restrict__ W1, const float* __restrict__ b1,
                                             const float* __restrict__ W2, const float* __restrict__ b2,
                                             const float* __restrict__ W3, const float* __restrict__ b3,
                                             const float* __restrict__ Wc, const float* __restrict__ bc,
                                             float* __restrict__ out) {
  __shared__ float xs[4][512];
  __shared__ float h1[4][256];
  __shared__ float h2[4][128];
  __shared__ float h3[4][64];
  int t = threadIdx.x;
  int r0 = blockIdx.x * 4;
  {
    const float4* src = (const float4*)(emb + (size_t)r0 * DIM);
    float4* dst = (float4*)&xs[0][0];
    dst[t] = src[t];
    dst[t + 256] = src[t + 256];
  }
  __syncthreads();
  {
    float a0 = 0.f, a1 = 0.f, a2 = 0.f, a3 = 0.f;
    for (int k = 0; k < 512; k++) {
      float w = W1[k * 256 + t];
      a0 = fmaf(xs[0][k], w, a0);
      a1 = fmaf(xs[1][k], w, a1);
      a2 = fmaf(xs[2][k], w, a2);
      a3 = fmaf(xs[3][k], w, a3);
    }
    float bb = b1[t];
    h1[0][t] = fmaxf(a0 + bb, 0.f);
    h1[1][t] = fmaxf(a1 + bb, 0.f);
    h1[2][t] = fmaxf(a2 + bb, 0.f);
    h1[3][t] = fmaxf(a3 + bb, 0.f);
  }
  __syncthreads();
  {
    int c = t & 127, rb = (t >> 7) * 2;
    float a0 = 0.f, a1 = 0.f;
    for (int k = 0; k < 256; k++) {
      float w = W2[k * 128 + c];
      a0 = fmaf(h1[rb][k], w, a0);
      a1 = fmaf(h1[rb + 1][k], w, a1);
    }
    float bb = b2[c];
    h2[rb][c] = fmaxf(a0 + bb, 0.f);
    h2[rb + 1][c] = fmaxf(a1 + bb, 0.f);
  }
  __syncthreads();
  {
    int c = t & 63, r = t >> 6;
    float a = 0.f;
    for (int k = 0; k < 128; k++) a = fmaf(h2[r][k], W3[k * 64 + c], a);
    h3[r][c] = fmaxf(a + b3[c], 0.f);
  }
  __syncthreads();
  {
    int r = t >> 6, l = t & 63;
    float v = h3[r][l] * Wc[l];
#pragma unroll
    for (int m = 32; m; m >>= 1) v += __shfl_down(v, m);
    if (l == 0) out[r0 + r] = v + bc[0];
  }
}

// ---------------------------------------------------------------------------
// Similarity, single-bf16 MFMA, SYMMETRY-reduced grid.
// Compute block (x,y) iff x>=32 (unlabeled i rows: all stores, direct &
// coalesced) or y<=x (labeled-labeled lower triangle: mean only).
// Mean weights: labeled off-diag tiles count twice (mirror not computed),
// labeled-unlabeled tiles (x>=32,y<32) count twice, everything else once.
// ---------------------------------------------------------------------------
__global__ __launch_bounds__(256) void k_simM(const ushort* __restrict__ Eb,
                                              const float* __restrict__ rn,
                                              ushort* __restrict__ A,
                                              double* __restrict__ meansum) {
  int x = blockIdx.x, y = blockIdx.y;
  if (x < 32 && y > x) return;                  // skip mirrored labeled tiles
  __shared__ ushort Ei[128 * 40];
  __shared__ ushort Ej[128 * 40];
  __shared__ float redbuf[4];

  int t = threadIdx.x;
  int w = t >> 6, lane = t & 63;
  int m = lane & 15, g = lane >> 4;
  int ib = (w >> 1) * 64, jb = (w & 1) * 64;
  int i0 = x * 128, j0 = y * 128;

  floatx4 acc[4][4];
#pragma unroll
  for (int a = 0; a < 4; a++)
#pragma unroll
    for (int b = 0; b < 4; b++) acc[a][b] = (floatx4)0.0f;

  int lrow = t >> 1, lhalf = (t & 1) * 16;
  for (int kt = 0; kt < DIM; kt += 32) {
    __syncthreads();
    {
      const ushort* gi = Eb + (size_t)(i0 + lrow) * DIM + kt + lhalf;
      const ushort* gj = Eb + (size_t)(j0 + lrow) * DIM + kt + lhalf;
      int o = lrow * 40 + lhalf;
      *(short8*)&Ei[o]     = *(const short8*)gi;
      *(short8*)&Ei[o + 8] = *(const short8*)(gi + 8);
      *(short8*)&Ej[o]     = *(const short8*)gj;
      *(short8*)&Ej[o + 8] = *(const short8*)(gj + 8);
    }
    __syncthreads();

    short8 ah[4], bh[4];
#pragma unroll
    for (int rt = 0; rt < 4; rt++) ah[rt] = *(const short8*)&Ei[(ib + rt * 16 + m) * 40 + g * 8];
#pragma unroll
    for (int ct = 0; ct < 4; ct++) bh[ct] = *(const short8*)&Ej[(jb + ct * 16 + m) * 40 + g * 8];
#pragma unroll
    for (int rt = 0; rt < 4; rt++)
#pragma unroll
      for (int ct = 0; ct < 4; ct++)
        acc[rt][ct] = __builtin_amdgcn_mfma_f32_16x16x32_bf16(ah[rt], bh[ct], acc[rt][ct], 0, 0, 0);
  }

  // epilogue (C/D map: col=lane&15, row=(lane>>4)*4+reg — verified r2/r3)
  bool dostore = (x >= 32);
  bool isdiag  = (x == y);
  float weight = (x < 32) ? (isdiag ? 1.0f : 2.0f) : ((y < 32) ? 2.0f : 1.0f);
  float lsum = 0.f;
#pragma unroll
  for (int rt = 0; rt < 4; rt++) {
    int gi0 = i0 + ib + rt * 16 + g * 4;
    float4 rni = *(const float4*)(rn + gi0);
#pragma unroll
    for (int ct = 0; ct < 4; ct++) {
      int gj = j0 + jb + ct * 16 + m;
      float rnj = rn[gj];
#pragma unroll
      for (int r = 0; r < 4; r++) {
        int gi = gi0 + r;
        float rv = (r == 0) ? rni.x : (r == 1) ? rni.y : (r == 2) ? rni.z : rni.w;
        float s = acc[rt][ct][r] * rv * rnj;
        if (isdiag && gi == gj) s = 0.f;
        s = fminf(fmaxf(s, 0.f), 1.f);
        lsum += s;
        if (dostore) A[(size_t)(gi - NLAB) * BROWS + gj] = f2bf(s);  // normal store (L2 merges)
      }
    }
  }
  lsum *= weight;
#pragma unroll
  for (int d = 1; d < 64; d <<= 1) lsum += __shfl_xor(lsum, d);
  if (lane == 0) redbuf[w] = lsum;
  __syncthreads();
  if (t == 0) atomicAdd(meansum, (double)(redbuf[0] + redbuf[1] + redbuf[2] + redbuf[3]));
}

// ---------------------------------------------------------------------------
// Fused iteration.  256 blocks x 512 thr (8 waves).  Block owns 16 unlabeled
// rows across the full K; waves split K; LDS-reduce; fused epilogue.
// it==0: reads raw S bf16, mean-thresholds in regs, rewrites A in place (own
// rows only -> race-free), saves labeled partial as Plab.  X^T ping-pong.
// Convergence: skip iff errsq[it-1] <= TOL^2 (skip chains -> exact while-loop).
// ---------------------------------------------------------------------------
__global__ __launch_bounds__(512) void k_iter(ushort* __restrict__ A,
                                              const ushort* __restrict__ XTr,
                                              ushort* __restrict__ XTw,
                                              float* __restrict__ Xu,
                                              float* __restrict__ Plab,
                                              float* __restrict__ hist,
                                              float* __restrict__ errsq,
                                              const double* __restrict__ ms,
                                              int it) {
  if (it > 0 && errsq[it - 1] <= 1e-6f) return;
  __shared__ float part[8][16 * 113];   // 57856 B
  __shared__ float Pbuf[16 * 114];      //  7296 B
  int t = threadIdx.x;
  int w = t >> 6, lane = t & 63;
  int m = lane & 15, g = lane >> 4;
  int r0 = blockIdx.x * 16;             // unlabeled row base (i' space)

  int kw, nch;
  float mean = 0.f;
  if (it == 0) { kw = w * 1024; nch = 32;
                 mean = (float)(ms[0] * (1.0 / ((double)BROWS * (double)BROWS))); }
  else         { kw = NLAB + w * 512; nch = 16; }

  floatx4 acc[7];
#pragma unroll
  for (int c = 0; c < 7; c++) acc[c] = (floatx4)0.0f;

  for (int ks = 0; ks < nch; ks++) {
    int kk = kw + ks * 32;
    size_t ao = (size_t)(r0 + m) * BROWS + kk + g * 8;
    short8 a = __builtin_nontemporal_load((const short8*)(A + ao));  // NT: keep L2 for X^T
    if (it == 0) {
      union { short8 v; ushort u[8]; } ua; ua.v = a;
#pragma unroll
      for (int e = 0; e < 8; e++) {
        float s = bf2f(ua.u[e]);
        float av = (s < mean) ? 1.0f : 1.0f - s;
        ua.u[e] = f2bf(av);
      }
      a = ua.v;
      *(short8*)(A + ao) = a;           // normal store: L2 write-combines
    }
#pragma unroll
    for (int ct = 0; ct < 7; ct++) {
      short8 b = *(const short8*)(XTr + (size_t)(ct * 16 + m) * BROWS + kk + g * 8);
      acc[ct] = __builtin_amdgcn_mfma_f32_16x16x32_bf16(a, b, acc[ct], 0, 0, 0);
    }
  }

  // wave partials -> LDS  (D row = g*4+r, col = ct*16+m)
#pragma unroll
  for (int ct = 0; ct < 7; ct++)
#pragma unroll
    for (int r = 0; r < 4; r++)
      part[w][(g * 4 + r) * 113 + ct * 16 + m] = acc[ct][r];
  __syncthreads();

  // reduce 8 partials; Plab store (it0) / add (it>0)
  for (int idx = t; idx < 16 * CPAD; idx += 512) {
    int row = idx / CPAD, col = idx % CPAD;
    int o = row * 113 + col;
    float s03 = part[0][o] + part[1][o] + part[2][o] + part[3][o];
    float s47 = part[4][o] + part[5][o] + part[6][o] + part[7][o];
    float P;
    size_t go = (size_t)(r0 + row) * CPAD + col;
    if (it == 0) { Plab[go] = s03; P = s03 + s47; }
    else         { P = s03 + s47 + Plab[go]; }
    Pbuf[row * 114 + col] = P;
  }
  __syncthreads();

  // fused epilogue: wave w handles rows 2w, 2w+1 (56 lanes x float2 = 112)
  float dsq_acc = 0.f;
#pragma unroll
  for (int rr = 0; rr < 2; rr++) {
    int row = w * 2 + rr;
    int gr = r0 + row;
    bool act = lane < 56;
    float2 p = make_float2(0.f, 0.f), xo = make_float2(0.f, 0.f);
    if (act) {
      p = *(const float2*)&Pbuf[row * 114 + lane * 2];
      xo = *(const float2*)(Xu + (size_t)gr * CPAD + lane * 2);
    }
    float2 xn;
    xn.x = xo.x * p.x;
    xn.y = xo.y * p.y;
    float s = xn.x + xn.y;
#pragma unroll
    for (int d = 1; d < 64; d <<= 1) s += __shfl_xor(s, d);
    float inv = 1.0f / s;
    float ent = 0.f, dsq = 0.f;
    if (act) {
      xn.x *= inv; xn.y *= inv;
      ent = -(xn.x * log2f(xn.x + 1e-20f) + xn.y * log2f(xn.y + 1e-20f));
      float dx = xn.x - xo.x, dy = xn.y - xo.y;
      dsq = dx * dx + dy * dy;
      *(float2*)(Xu + (size_t)gr * CPAD + lane * 2) = xn;
      int c0 = lane * 2, jg = NLAB + gr;
      XTw[(size_t)c0 * BROWS + jg]       = f2bf(xn.x);
      XTw[(size_t)(c0 + 1) * BROWS + jg] = f2bf(xn.y);
    }
#pragma unroll
    for (int d = 1; d < 64; d <<= 1) { ent += __shfl_xor(ent, d); dsq += __shfl_xor(dsq, d); }
    if (lane == 0) {
      hist[gr] += ent;
      dsq_acc += dsq;
    }
  }
  if (lane == 0) atomicAdd(&errsq[it], dsq_acc);
}

__global__ __launch_bounds__(256) void k_final(const float* __restrict__ hist,
                                               float* __restrict__ out) {
  int i = blockIdx.x * 256 + threadIdx.x;
  float yt = (i < NLAB) ? 0.0f : hist[i - NLAB] * (1.0f / 30.0f);
  out[BROWS + i] = yt;
  out[2 * BROWS + i] = (i < NLAB) ? 1.0f : 0.0f;
}

// ---------------------------------------------------------------------------
extern "C" void kernel_launch(void* const* d_in, const int* in_sizes, int n_in,
                              void* d_out, int out_size, void* d_ws, size_t ws_size,
                              hipStream_t stream) {
  const float* emb    = (const float*)d_in[1];
  const int*   labels = (const int*)d_in[2];
  const float* W1 = (const float*)d_in[3];
  const float* b1 = (const float*)d_in[4];
  const float* W2 = (const float*)d_in[5];
  const float* b2 = (const float*)d_in[6];
  const float* W3 = (const float*)d_in[7];
  const float* b3 = (const float*)d_in[8];
  const float* Wc = (const float*)d_in[9];
  const float* bc = (const float*)d_in[10];
  float* out = (float*)d_out;

  char* ws = (char*)d_ws;
  ushort* A    = (ushort*)(ws + OFF_A);
  ushort* Eb   = (ushort*)(ws + OFF_EB);
  ushort* XT0  = (ushort*)(ws + OFF_XT0);
  ushort* XT1  = (ushort*)(ws + OFF_XT1);
  float*  Xu   = (float*)(ws + OFF_XU);
  float*  Plab = (float*)(ws + OFF_PL);
  float*  hist = (float*)(ws + OFF_HIST);
  float*  errs = (float*)(ws + OFF_ERR);
  double* ms   = (double*)(ws + OFF_MS);
  float*  rn   = (float*)(ws + OFF_RN);

  // zero hist + errsq + mean accumulator
  hipMemsetAsync(ws + OFF_HIST, 0, (OFF_MS - OFF_HIST) + 8, stream);

  k_rnorm<<<BROWS, 64, 0, stream>>>(emb, rn);
  k_prep<<<(BROWS * DIM) / 8 / 256, 256, 0, stream>>>(emb, Eb);
  k_mlp<<<BROWS / 4, 256, 0, stream>>>(emb, W1, b1, W2, b2, W3, b3, Wc, bc, out);

  { dim3 g(BROWS / 128, BROWS / 128); k_simM<<<g, 256, 0, stream>>>(Eb, rn, A, ms); }

  // overlay init (Eb dead now)
  k_initXu<<<(NUNL * CPAD) / 256, 256, 0, stream>>>(Xu);
  { dim3 g(BROWS / 256, CPAD); k_initXT<<<g, 256, 0, stream>>>(XT0, XT1, labels); }

  for (int it = 0; it < MAXIT; it++) {
    const ushort* XTr = (it & 1) ? XT1 : XT0;
    ushort*       XTw = (it & 1) ? XT0 : XT1;
    k_iter<<<NUNL / 16, 512, 0, stream>>>(A, XTr, XTw, Xu, Plab, hist, errs, ms, it);
  }

  k_final<<<BROWS / 256, 256, 0, stream>>>(hist, out);
}